// Round 1
// baseline (1023.163 us; speedup 1.0000x reference)
//
#include <hip/hip_runtime.h>

#define NTOK 8192
#define IDIM 1024
#define HDIM 4096
#define ODIM 1024
#define NEXP 8
#define ROWCAP 17408          // NTOK*2 + NEXP*128 = 17408 padded rows max
#define GATE_BLOCKS 128

typedef unsigned short u16;
typedef __attribute__((ext_vector_type(8))) __bf16 bf16x8;
typedef __attribute__((ext_vector_type(8))) short short8;
typedef __attribute__((ext_vector_type(4))) float f32x4;
typedef __attribute__((ext_vector_type(4))) unsigned short u16x4;
typedef __attribute__((ext_vector_type(8))) unsigned short u16x8;

__device__ __forceinline__ u16 f2bf(float f) {
  union { float f; unsigned u; } c; c.f = f;
  unsigned u = c.u;
  return (u16)((u + 0x7fffu + ((u >> 16) & 1u)) >> 16);
}
__device__ __forceinline__ float bf2f(u16 h) {
  union { unsigned u; float f; } c; c.u = ((unsigned)h) << 16;
  return c.f;
}
__device__ __forceinline__ void gload16(const void* g, void* l) {
  __builtin_amdgcn_global_load_lds((const __attribute__((address_space(1))) unsigned*)g,
                                   (__attribute__((address_space(3))) unsigned*)l, 16, 0, 0);
}

// ---------------- convert x: f32 -> bf16 ----------------
__global__ __launch_bounds__(256) void convert_x_kernel(const float* __restrict__ in,
                                                        u16* __restrict__ out) {
  int i = (blockIdx.x * 256 + threadIdx.x) * 4;
  f32x4 v = *(const f32x4*)(in + i);
  u16x4 o;
  #pragma unroll
  for (int j = 0; j < 4; ++j) o[j] = f2bf(v[j]);
  *(u16x4*)(out + i) = o;
}

// ---------------- transpose-convert: in [R][C] f32 -> out [C][R] bf16 (per blockIdx.z matrix) ---
__global__ __launch_bounds__(256) void transpose_convert_kernel(const float* __restrict__ in,
                                                                u16* __restrict__ out,
                                                                int R, int C) {
  __shared__ float tile[32][33];
  size_t msize = (size_t)R * C;
  const float* ip = in + (size_t)blockIdx.z * msize;
  u16* op = out + (size_t)blockIdx.z * msize;
  int c0 = blockIdx.x * 32, r0 = blockIdx.y * 32;
  int tx = threadIdx.x & 31, ty = threadIdx.x >> 5;
  #pragma unroll
  for (int k = 0; k < 4; ++k) {
    int r = ty + k * 8;
    tile[r][tx] = ip[(size_t)(r0 + r) * C + (c0 + tx)];
  }
  __syncthreads();
  #pragma unroll
  for (int k = 0; k < 4; ++k) {
    int c = ty + k * 8;
    op[(size_t)(c0 + c) * R + (r0 + tx)] = f2bf(tile[tx][c]);
  }
}

// ---------------- gating: f32 logits, softmax, top-2, routing lists, imp partials ----------------
__global__ __launch_bounds__(256) void gating_kernel(
    const float* __restrict__ x, const float* __restrict__ wg, const float* __restrict__ bg,
    float* __restrict__ combine, int* __restrict__ tokenlist, int* __restrict__ cnt,
    float* __restrict__ imp_partial) {
  __shared__ float wgs[NEXP][IDIM];   // transposed gate weights, conflict-free reads
  __shared__ float impw[4][NEXP];
  int tid = threadIdx.x;
  for (int t = tid; t < IDIM * NEXP; t += 256) {
    int i = t >> 3, e = t & 7;
    wgs[e][i] = wg[t];
  }
  __syncthreads();
  int wave = tid >> 6, lane = tid & 63;
  float impacc[NEXP];
  #pragma unroll
  for (int e = 0; e < NEXP; ++e) impacc[e] = 0.f;

  for (int it = 0; it < 16; ++it) {
    int t = blockIdx.x * 64 + wave * 16 + it;
    const float* xr = x + (size_t)t * IDIM;
    float s[NEXP];
    #pragma unroll
    for (int e = 0; e < NEXP; ++e) s[e] = 0.f;
    for (int ii = 0; ii < IDIM / 64; ++ii) {
      float xv = xr[lane + ii * 64];
      int li = lane + ii * 64;
      #pragma unroll
      for (int e = 0; e < NEXP; ++e) s[e] = fmaf(xv, wgs[e][li], s[e]);
    }
    #pragma unroll
    for (int e = 0; e < NEXP; ++e) {
      #pragma unroll
      for (int off = 32; off; off >>= 1) s[e] += __shfl_xor(s[e], off);
    }
    if (lane == 0) {
      #pragma unroll
      for (int e = 0; e < NEXP; ++e) s[e] += bg[e];
      // top-2 on logits (softmax monotonic; ties -> lowest index like lax.top_k)
      int i1 = 0; float v1 = s[0];
      #pragma unroll
      for (int e = 1; e < NEXP; ++e) if (s[e] > v1) { v1 = s[e]; i1 = e; }
      int i2 = -1; float v2 = -1e30f;
      #pragma unroll
      for (int e = 0; e < NEXP; ++e) if (e != i1 && s[e] > v2) { v2 = s[e]; i2 = e; }
      // full softmax for imp
      float p[NEXP], sum = 0.f;
      #pragma unroll
      for (int e = 0; e < NEXP; ++e) { p[e] = __expf(s[e] - v1) * 0.f + expf(s[e] - v1); sum += p[e]; }
      float inv = 1.f / sum;
      #pragma unroll
      for (int e = 0; e < NEXP; ++e) { p[e] *= inv; impacc[e] += p[e]; }
      // renormalized top-2 weights (exact algebra, no dynamic reg index)
      float c1 = 1.f / (1.f + expf(v2 - v1));
      float c2 = 1.f - c1;
      #pragma unroll
      for (int e = 0; e < NEXP; ++e) combine[(size_t)t * NEXP + e] = 0.f;
      combine[(size_t)t * NEXP + i1] = c1;
      combine[(size_t)t * NEXP + i2] = c2;
      int s1 = atomicAdd(&cnt[i1], 1); tokenlist[i1 * NTOK + s1] = t;
      int s2 = atomicAdd(&cnt[i2], 1); tokenlist[i2 * NTOK + s2] = t;
    }
  }
  if (lane == 0) {
    #pragma unroll
    for (int e = 0; e < NEXP; ++e) impw[wave][e] = impacc[e];
  }
  __syncthreads();
  if (tid == 0) {
    #pragma unroll
    for (int e = 0; e < NEXP; ++e)
      imp_partial[blockIdx.x * NEXP + e] = impw[0][e] + impw[1][e] + impw[2][e] + impw[3][e];
  }
}

// ---------------- offsets (padded prefix sums) + aux loss ----------------
__global__ __launch_bounds__(64) void offsets_aux_kernel(
    const int* __restrict__ cnt, const float* __restrict__ imp_partial,
    int* __restrict__ offsets, float* __restrict__ aux_out) {
  __shared__ float imp[NEXP];
  int tid = threadIdx.x;
  if (tid < NEXP) {
    float v = 0.f;
    for (int b = 0; b < GATE_BLOCKS; ++b) v += imp_partial[b * NEXP + tid];
    imp[tid] = v;
  }
  __syncthreads();
  if (tid == 0) {
    int off = 0;
    for (int e = 0; e < NEXP; ++e) { offsets[e] = off; off += (cnt[e] + 127) & ~127; }
    offsets[NEXP] = off;
    double im = 0.0;
    for (int e = 0; e < NEXP; ++e) im += imp[e];
    im /= NEXP;
    double iv = 0.0;
    for (int e = 0; e < NEXP; ++e) { double d = (double)imp[e] - im; iv += d * d; }
    iv /= (NEXP - 1);
    double il = sqrt(iv) / (im + 1e-6); il = il * il;
    double lm = 0.0;
    for (int e = 0; e < NEXP; ++e) lm += cnt[e];
    lm /= (double)NEXP * NTOK;
    double lv = 0.0;
    for (int e = 0; e < NEXP; ++e) { double d = (double)cnt[e] / NTOK - lm; lv += d * d; }
    lv /= (NEXP - 1);
    double ll = sqrt(lv) / (lm + 1e-6); ll = ll * ll;
    aux_out[0] = (float)(il + ll);
  }
}

// ---------------- GEMM1: gathered x rows @ w1T -> Hpre (bf16, +b1) ----------------
__global__ __launch_bounds__(256) void gemm1_kernel(
    const u16* __restrict__ xb, const u16* __restrict__ w1t, const float* __restrict__ b1,
    const int* __restrict__ tokenlist, const int* __restrict__ cnt,
    const int* __restrict__ offsets, u16* __restrict__ Hbuf) {
  __shared__ __align__(16) u16 As[128 * 32];
  __shared__ __align__(16) u16 Bs[128 * 32];
  int grb = blockIdx.y * 128;
  if (grb >= offsets[NEXP]) return;
  int e = 0;
  #pragma unroll
  for (int k = 0; k < NEXP - 1; ++k) if (grb >= offsets[k + 1]) e = k + 1;
  int lr0 = grb - offsets[e];
  int cnt_e = cnt[e];
  int cb = blockIdx.x;
  int tid = threadIdx.x, lane = tid & 63, wave = tid >> 6;

  const int* tl = tokenlist + e * NTOK;
  int rA0 = lr0 + wave * 32 + (lane >> 2);
  int t0 = tl[min(rA0, cnt_e - 1)];
  int t1 = tl[min(rA0 + 16, cnt_e - 1)];
  const u16* ga0 = xb + (size_t)t0 * IDIM + (lane & 3) * 8;
  const u16* ga1 = xb + (size_t)t1 * IDIM + (lane & 3) * 8;
  int nb0 = cb * 128 + wave * 32 + (lane >> 2);
  const u16* gb0 = w1t + ((size_t)e * HDIM + nb0) * IDIM + (lane & 3) * 8;
  const u16* gb1 = gb0 + (size_t)16 * IDIM;
  u16* lA0 = As + (wave * 2 + 0) * 512;
  u16* lA1 = As + (wave * 2 + 1) * 512;
  u16* lB0 = Bs + (wave * 2 + 0) * 512;
  u16* lB1 = Bs + (wave * 2 + 1) * 512;

  int wr = wave >> 1, wc = wave & 1;
  f32x4 acc[4][4];
  #pragma unroll
  for (int m = 0; m < 4; ++m)
    #pragma unroll
    for (int n = 0; n < 4; ++n) acc[m][n] = (f32x4){0.f, 0.f, 0.f, 0.f};

  for (int kt = 0; kt < IDIM / 32; ++kt) {
    int k0 = kt * 32;
    gload16(ga0 + k0, lA0);
    gload16(ga1 + k0, lA1);
    gload16(gb0 + k0, lB0);
    gload16(gb1 + k0, lB1);
    __syncthreads();
    bf16x8 af[4], bfr[4];
    #pragma unroll
    for (int m = 0; m < 4; ++m)
      af[m] = *(const bf16x8*)(As + (wr * 64 + m * 16 + (lane & 15)) * 32 + (lane >> 4) * 8);
    #pragma unroll
    for (int n = 0; n < 4; ++n)
      bfr[n] = *(const bf16x8*)(Bs + (wc * 64 + n * 16 + (lane & 15)) * 32 + (lane >> 4) * 8);
    #pragma unroll
    for (int m = 0; m < 4; ++m)
      #pragma unroll
      for (int n = 0; n < 4; ++n)
        acc[m][n] = __builtin_amdgcn_mfma_f32_16x16x32_bf16(af[m], bfr[n], acc[m][n], 0, 0, 0);
    __syncthreads();
  }

  #pragma unroll
  for (int n = 0; n < 4; ++n) {
    int col = cb * 128 + wc * 64 + n * 16 + (lane & 15);
    float bias = b1[e * HDIM + col];
    #pragma unroll
    for (int m = 0; m < 4; ++m) {
      #pragma unroll
      for (int j = 0; j < 4; ++j) {
        int grow = grb + wr * 64 + m * 16 + (lane >> 4) * 4 + j;
        Hbuf[(size_t)grow * HDIM + col] = f2bf(acc[m][n][j] + bias);
      }
    }
  }
}

// ---------------- LN (biased var, eps 1e-5) + exact GELU, in place on Hbuf rows ----------------
__global__ __launch_bounds__(256) void ln_gelu_kernel(
    u16* __restrict__ Hbuf, const float* __restrict__ g, const float* __restrict__ b,
    const int* __restrict__ offsets) {
  int r = blockIdx.x;
  if (r >= offsets[NEXP]) return;
  int e = 0;
  #pragma unroll
  for (int k = 0; k < NEXP - 1; ++k) if (r >= offsets[k + 1]) e = k + 1;
  u16* row = Hbuf + (size_t)r * HDIM;
  int tid = threadIdx.x;
  float s = 0.f, ss = 0.f;
  short8 v[2];
  #pragma unroll
  for (int it = 0; it < 2; ++it) {
    v[it] = *(const short8*)(row + (tid + it * 256) * 8);
    #pragma unroll
    for (int j = 0; j < 8; ++j) { float f = bf2f((u16)v[it][j]); s += f; ss += f * f; }
  }
  #pragma unroll
  for (int off = 32; off; off >>= 1) { s += __shfl_xor(s, off); ss += __shfl_xor(ss, off); }
  __shared__ float rs[4], rss[4];
  int wave = tid >> 6, lane = tid & 63;
  if (lane == 0) { rs[wave] = s; rss[wave] = ss; }
  __syncthreads();
  float S = rs[0] + rs[1] + rs[2] + rs[3];
  float SS = rss[0] + rss[1] + rss[2] + rss[3];
  float mean = S * (1.f / HDIM);
  float var = SS * (1.f / HDIM) - mean * mean;
  float rstd = rsqrtf(var + 1e-5f);
  #pragma unroll
  for (int it = 0; it < 2; ++it) {
    int base = (tid + it * 256) * 8;
    u16x8 o;
    #pragma unroll
    for (int j = 0; j < 8; ++j) {
      float f = bf2f((u16)v[it][j]);
      float y = (f - mean) * rstd * g[e * HDIM + base + j] + b[e * HDIM + base + j];
      float gel = 0.5f * y * (1.f + erff(y * 0.70710678118654752f));
      o[j] = f2bf(gel);
    }
    *(u16x8*)(row + base) = o;
  }
}

// ---------------- GEMM2: Hact @ w2T, epilogue atomicAdd c*(acc+b2) into out_accum ----------------
__global__ __launch_bounds__(256) void gemm2_kernel(
    const u16* __restrict__ Hbuf, const u16* __restrict__ w2t, const float* __restrict__ b2,
    const int* __restrict__ tokenlist, const int* __restrict__ cnt,
    const int* __restrict__ offsets, const float* __restrict__ combine,
    float* __restrict__ out_accum) {
  __shared__ __align__(16) u16 As[128 * 32];
  __shared__ __align__(16) u16 Bs[128 * 32];
  int grb = blockIdx.y * 128;
  if (grb >= offsets[NEXP]) return;
  int e = 0;
  #pragma unroll
  for (int k = 0; k < NEXP - 1; ++k) if (grb >= offsets[k + 1]) e = k + 1;
  int lr0 = grb - offsets[e];
  int cnt_e = cnt[e];
  int cb = blockIdx.x;
  int tid = threadIdx.x, lane = tid & 63, wave = tid >> 6;

  const int* tl = tokenlist + e * NTOK;
  int rA0 = grb + wave * 32 + (lane >> 2);  // global padded row (contiguous, no gather)
  const u16* ga0 = Hbuf + (size_t)rA0 * HDIM + (lane & 3) * 8;
  const u16* ga1 = ga0 + (size_t)16 * HDIM;
  int nb0 = cb * 128 + wave * 32 + (lane >> 2);
  const u16* gb0 = w2t + ((size_t)e * ODIM + nb0) * HDIM + (lane & 3) * 8;
  const u16* gb1 = gb0 + (size_t)16 * HDIM;
  u16* lA0 = As + (wave * 2 + 0) * 512;
  u16* lA1 = As + (wave * 2 + 1) * 512;
  u16* lB0 = Bs + (wave * 2 + 0) * 512;
  u16* lB1 = Bs + (wave * 2 + 1) * 512;

  int wr = wave >> 1, wc = wave & 1;
  f32x4 acc[4][4];
  #pragma unroll
  for (int m = 0; m < 4; ++m)
    #pragma unroll
    for (int n = 0; n < 4; ++n) acc[m][n] = (f32x4){0.f, 0.f, 0.f, 0.f};

  for (int kt = 0; kt < HDIM / 32; ++kt) {
    int k0 = kt * 32;
    gload16(ga0 + k0, lA0);
    gload16(ga1 + k0, lA1);
    gload16(gb0 + k0, lB0);
    gload16(gb1 + k0, lB1);
    __syncthreads();
    bf16x8 af[4], bfr[4];
    #pragma unroll
    for (int m = 0; m < 4; ++m)
      af[m] = *(const bf16x8*)(As + (wr * 64 + m * 16 + (lane & 15)) * 32 + (lane >> 4) * 8);
    #pragma unroll
    for (int n = 0; n < 4; ++n)
      bfr[n] = *(const bf16x8*)(Bs + (wc * 64 + n * 16 + (lane & 15)) * 32 + (lane >> 4) * 8);
    #pragma unroll
    for (int m = 0; m < 4; ++m)
      #pragma unroll
      for (int n = 0; n < 4; ++n)
        acc[m][n] = __builtin_amdgcn_mfma_f32_16x16x32_bf16(af[m], bfr[n], acc[m][n], 0, 0, 0);
    __syncthreads();
  }

  float bias_n[4];
  #pragma unroll
  for (int n = 0; n < 4; ++n)
    bias_n[n] = b2[e * ODIM + cb * 128 + wc * 64 + n * 16 + (lane & 15)];
  #pragma unroll
  for (int m = 0; m < 4; ++m) {
    #pragma unroll
    for (int j = 0; j < 4; ++j) {
      int lrow = lr0 + wr * 64 + m * 16 + (lane >> 4) * 4 + j;
      if (lrow < cnt_e) {
        int tok = tl[lrow];
        float c = combine[(size_t)tok * NEXP + e];
        #pragma unroll
        for (int n = 0; n < 4; ++n) {
          int col = cb * 128 + wc * 64 + n * 16 + (lane & 15);
          atomicAdd(&out_accum[(size_t)tok * ODIM + col], c * (acc[m][n][j] + bias_n[n]));
        }
      }
    }
  }
}

// ---------------- final LN over O=1024, f32 out ----------------
__global__ __launch_bounds__(256) void final_ln_kernel(
    const float* __restrict__ accp, const float* __restrict__ g, const float* __restrict__ b,
    float* __restrict__ out) {
  int t = blockIdx.x;
  int tid = threadIdx.x;
  const float* row = accp + (size_t)t * ODIM;
  f32x4 v = *(const f32x4*)(row + tid * 4);
  float s = v[0] + v[1] + v[2] + v[3];
  float ss = v[0] * v[0] + v[1] * v[1] + v[2] * v[2] + v[3] * v[3];
  #pragma unroll
  for (int off = 32; off; off >>= 1) { s += __shfl_xor(s, off); ss += __shfl_xor(ss, off); }
  __shared__ float rs[4], rss[4];
  int wave = tid >> 6, lane = tid & 63;
  if (lane == 0) { rs[wave] = s; rss[wave] = ss; }
  __syncthreads();
  float S = rs[0] + rs[1] + rs[2] + rs[3];
  float SS = rss[0] + rss[1] + rss[2] + rss[3];
  float mean = S * (1.f / ODIM);
  float var = SS * (1.f / ODIM) - mean * mean;
  float rstd = rsqrtf(var + 1e-5f);
  f32x4 gv = *(const f32x4*)(g + tid * 4);
  f32x4 bv = *(const f32x4*)(b + tid * 4);
  f32x4 o;
  #pragma unroll
  for (int j = 0; j < 4; ++j) o[j] = (v[j] - mean) * rstd * gv[j] + bv[j];
  *(f32x4*)(out + (size_t)t * ODIM + tid * 4) = o;
}

extern "C" void kernel_launch(void* const* d_in, const int* in_sizes, int n_in,
                              void* d_out, int out_size, void* d_ws, size_t ws_size,
                              hipStream_t stream) {
  (void)in_sizes; (void)n_in; (void)out_size; (void)ws_size;
  const float* x    = (const float*)d_in[0];
  const float* w1   = (const float*)d_in[1];
  const float* b1   = (const float*)d_in[2];
  const float* ln1g = (const float*)d_in[3];
  const float* ln1b = (const float*)d_in[4];
  const float* w2   = (const float*)d_in[5];
  const float* b2   = (const float*)d_in[6];
  const float* wg   = (const float*)d_in[7];
  const float* bg   = (const float*)d_in[8];
  const float* outg = (const float*)d_in[9];
  const float* outb = (const float*)d_in[10];
  float* out = (float*)d_out;

  char* ws = (char*)d_ws;
  size_t off = 0;
  auto alloc = [&](size_t bytes) {
    char* p = ws + off;
    off += (bytes + 255) & ~(size_t)255;
    return p;
  };
  u16* xb        = (u16*)alloc((size_t)NTOK * IDIM * 2);
  u16* w1t       = (u16*)alloc((size_t)NEXP * HDIM * IDIM * 2);
  u16* w2t       = (u16*)alloc((size_t)NEXP * ODIM * HDIM * 2);
  u16* Hbuf      = (u16*)alloc((size_t)ROWCAP * HDIM * 2);
  float* combine = (float*)alloc((size_t)NTOK * NEXP * 4);
  int* tokenlist = (int*)alloc((size_t)NEXP * NTOK * 4);
  int* cnt       = (int*)alloc(64);
  int* offsets   = (int*)alloc(64);
  float* imp_partial = (float*)alloc(GATE_BLOCKS * NEXP * 4);
  float* out_accum   = (float*)alloc((size_t)NTOK * ODIM * 4);

  hipMemsetAsync(cnt, 0, 64, stream);
  hipMemsetAsync(out_accum, 0, (size_t)NTOK * ODIM * 4, stream);

  convert_x_kernel<<<NTOK * IDIM / 1024, 256, 0, stream>>>(x, xb);
  transpose_convert_kernel<<<dim3(HDIM / 32, IDIM / 32, NEXP), 256, 0, stream>>>(w1, w1t, IDIM, HDIM);
  transpose_convert_kernel<<<dim3(ODIM / 32, HDIM / 32, NEXP), 256, 0, stream>>>(w2, w2t, HDIM, ODIM);
  gating_kernel<<<GATE_BLOCKS, 256, 0, stream>>>(x, wg, bg, combine, tokenlist, cnt, imp_partial);
  offsets_aux_kernel<<<1, 64, 0, stream>>>(cnt, imp_partial, offsets, out + (size_t)NTOK * ODIM);
  gemm1_kernel<<<dim3(HDIM / 128, ROWCAP / 128), 256, 0, stream>>>(xb, w1t, b1, tokenlist, cnt, offsets, Hbuf);
  ln_gelu_kernel<<<ROWCAP, 256, 0, stream>>>(Hbuf, ln1g, ln1b, offsets);
  gemm2_kernel<<<dim3(ODIM / 128, ROWCAP / 128), 256, 0, stream>>>(Hbuf, w2t, b2, tokenlist, cnt, offsets, combine, out_accum);
  final_ln_kernel<<<NTOK, 256, 0, stream>>>(out_accum, outg, outb, out);
}